// Round 1
// baseline (801.217 us; speedup 1.0000x reference)
//
#include <hip/hip_runtime.h>
#include <hip/hip_bf16.h>
#include <stdint.h>

#define NB 8
#define NS 4096
#define NHID 1024
#define NHEAD 16
#define ND 64
// rows = NB*NS = 32768, K = 1024, fused N = 2048

typedef __attribute__((ext_vector_type(8))) __bf16 bf16x8;
typedef __attribute__((ext_vector_type(4))) __bf16 bf16x4;
typedef __attribute__((ext_vector_type(4))) float floatx4;

__device__ __forceinline__ void async_copy16(const __bf16* g, __bf16* l) {
  __builtin_amdgcn_global_load_lds(
      (const __attribute__((address_space(1))) void*)g,
      (__attribute__((address_space(3))) void*)l,
      16, 0, 0);
}

__global__ void cast_f32_to_bf16(const float* __restrict__ in,
                                 __bf16* __restrict__ out, int n) {
  int i = (blockIdx.x * blockDim.x + threadIdx.x) * 4;
  int stride = gridDim.x * blockDim.x * 4;
  for (; i < n; i += stride) {
    float4 v = *(const float4*)(in + i);
    bf16x4 o;
    o[0] = (__bf16)v.x; o[1] = (__bf16)v.y; o[2] = (__bf16)v.z; o[3] = (__bf16)v.w;
    *(bf16x4*)(out + i) = o;
  }
}

// C[row, col] = sum_k A[row,k] * W[col,k]  (+bias); col<1024 -> Q, else KV.
__global__ __launch_bounds__(256) void gemm_qkv(
    const __bf16* __restrict__ A,   // [32768][1024]
    const __bf16* __restrict__ W,   // [2048][1024] rows: 0..1023 Wq, 1024..2047 Wkv
    const float* __restrict__ bq, const float* __restrict__ bkv,
    __bf16* __restrict__ Q, __bf16* __restrict__ KV) {
  __shared__ __align__(16) __bf16 As[128 * 64];
  __shared__ __align__(16) __bf16 Bs[128 * 64];
  const int tid  = threadIdx.x;
  const int lane = tid & 63;
  const int wid  = tid >> 6;
  const int tn = blockIdx.x & 15;   // N fastest: 16 consecutive blocks share A panel
  const int tm = blockIdx.x >> 4;
  const int rowBase = tm * 128;
  const int colBase = tn * 128;
  const int wm = wid >> 1, wn = wid & 1;

  floatx4 acc[4][4];
#pragma unroll
  for (int m = 0; m < 4; m++)
#pragma unroll
    for (int n = 0; n < 4; n++)
#pragma unroll
      for (int j = 0; j < 4; j++) acc[m][n][j] = 0.f;

  const int lrow = lane >> 3;        // 0..7
  const int lk   = (lane & 7) * 8;   // 0..56

  for (int kt = 0; kt < 1024; kt += 64) {
#pragma unroll
    for (int i = 0; i < 4; ++i) {
      const int chunk = wid * 4 + i;        // 0..15
      const int r = chunk * 8 + lrow;       // 0..127
      async_copy16(A + (size_t)(rowBase + r) * 1024 + kt + lk, &As[chunk * 512]);
      async_copy16(W + (size_t)(colBase + r) * 1024 + kt + lk, &Bs[chunk * 512]);
    }
    __syncthreads();
#pragma unroll
    for (int ks = 0; ks < 64; ks += 32) {
      bf16x8 af[4], bfr[4];
#pragma unroll
      for (int m = 0; m < 4; m++)
        af[m] = *(const bf16x8*)&As[(wm * 64 + m * 16 + (lane & 15)) * 64 + ks + (lane >> 4) * 8];
#pragma unroll
      for (int n = 0; n < 4; n++)
        bfr[n] = *(const bf16x8*)&Bs[(wn * 64 + n * 16 + (lane & 15)) * 64 + ks + (lane >> 4) * 8];
#pragma unroll
      for (int m = 0; m < 4; m++)
#pragma unroll
        for (int n = 0; n < 4; n++)
          acc[m][n] = __builtin_amdgcn_mfma_f32_16x16x32_bf16(af[m], bfr[n], acc[m][n], 0, 0, 0);
    }
    __syncthreads();
  }
  // epilogue: C/D layout col=lane&15, row=(lane>>4)*4+j
  const int crow0 = (lane >> 4) * 4;
  const int ccol  = lane & 15;
#pragma unroll
  for (int m = 0; m < 4; m++) {
#pragma unroll
    for (int n = 0; n < 4; n++) {
      const int col = colBase + wn * 64 + n * 16 + ccol;
      const float bias = (col < 1024) ? bq[col] : bkv[col - 1024];
#pragma unroll
      for (int j = 0; j < 4; j++) {
        const int row = rowBase + wm * 64 + m * 16 + crow0 + j;
        const float v = acc[m][n][j] + bias;
        if (col < 1024) Q[(size_t)row * 1024 + col] = (__bf16)v;
        else            KV[(size_t)row * 1024 + (col - 1024)] = (__bf16)v;
      }
    }
  }
}

// One block per (b, h): softmax(gq . k_s) over S, g_vec = sum attn * k.
__global__ __launch_bounds__(256) void global_attn(
    const __bf16* __restrict__ Q, const __bf16* __restrict__ KV,
    const float* __restrict__ mask, float* __restrict__ gvec,
    float* __restrict__ ctx) {
  __shared__ float sc[4096];
  __shared__ float red[256];
  __shared__ float gq[64];
  const int b = blockIdx.x >> 4;
  const int h = blockIdx.x & 15;
  const int tid = threadIdx.x;
  const float scale = 0.125f;
  if (tid < 64) gq[tid] = (float)Q[(size_t)(b * NS) * NHID + h * 64 + tid];
  __syncthreads();
  for (int s = tid; s < NS; s += 256) {
    const __bf16* kr = KV + (size_t)(b * NS + s) * NHID + h * 64;
    float dot = 0.f;
#pragma unroll
    for (int d0 = 0; d0 < 64; d0 += 8) {
      bf16x8 kv8 = *(const bf16x8*)(kr + d0);
#pragma unroll
      for (int j = 0; j < 8; j++) dot += gq[d0 + j] * (float)kv8[j];
    }
    sc[s] = dot * scale + mask[b * NS + s];
  }
  __syncthreads();
  float m = -1e30f;
  for (int s = tid; s < NS; s += 256) m = fmaxf(m, sc[s]);
  red[tid] = m; __syncthreads();
  for (int off = 128; off > 0; off >>= 1) {
    if (tid < off) red[tid] = fmaxf(red[tid], red[tid + off]);
    __syncthreads();
  }
  m = red[0]; __syncthreads();
  float lsum = 0.f;
  for (int s = tid; s < NS; s += 256) { float p = __expf(sc[s] - m); sc[s] = p; lsum += p; }
  red[tid] = lsum; __syncthreads();
  for (int off = 128; off > 0; off >>= 1) {
    if (tid < off) red[tid] += red[tid + off];
    __syncthreads();
  }
  const float tot = red[0];
  __syncthreads();
  const int d = tid & 63;
  const int chunk = tid >> 6;
  float accv = 0.f;
  for (int s = chunk * 1024; s < chunk * 1024 + 1024; ++s)
    accv += sc[s] * (float)KV[(size_t)(b * NS + s) * NHID + h * 64 + d];
  red[tid] = accv; __syncthreads();
  if (tid < 64) {
    const float g = (red[tid] + red[tid + 64] + red[tid + 128] + red[tid + 192]) / tot;
    gvec[(b * NHEAD + h) * 64 + tid] = g;
    ctx[(size_t)(b * NS) * NHID + h * 64 + tid] = g;  // ctx row s=0
  }
}

// One wave per (b, s>=1); 4 lanes per head.
__global__ __launch_bounds__(256) void local_attn(
    const __bf16* __restrict__ Q, const __bf16* __restrict__ KV,
    const float* __restrict__ gvec, float* __restrict__ ctx,
    float* __restrict__ lattn) {
  __shared__ float gs[NHEAD * 64];
  const int bb = blockIdx.x >> 10;
  const int s0 = (blockIdx.x & 1023) * 4;
  const int tid = threadIdx.x;
  for (int i = tid; i < NHEAD * 64; i += 256) gs[i] = gvec[bb * NHEAD * 64 + i];
  __syncthreads();
  const int wid = tid >> 6, lane = tid & 63;
  const int s = s0 + wid;
  if (s == 0) return;  // row 0 written by global_attn
  const int head = lane >> 2;
  const int dp = (lane & 3) * 16;
  const size_t rowoff = (size_t)(bb * NS + s) * NHID;
  const __bf16* qr = Q + rowoff + head * 64 + dp;
  const __bf16* kr = KV + rowoff + head * 64 + dp;
  float qv[16], kvv[16], gv[16];
  bf16x8 q0 = *(const bf16x8*)qr, q1 = *(const bf16x8*)(qr + 8);
  bf16x8 k0 = *(const bf16x8*)kr, k1 = *(const bf16x8*)(kr + 8);
#pragma unroll
  for (int j = 0; j < 8; j++) {
    qv[j] = (float)q0[j]; qv[j + 8] = (float)q1[j];
    kvv[j] = (float)k0[j]; kvv[j + 8] = (float)k1[j];
  }
#pragma unroll
  for (int j = 0; j < 16; j++) gv[j] = gs[head * 64 + dp + j];
  float sself = 0.f, sglob = 0.f;
#pragma unroll
  for (int j = 0; j < 16; j++) { sself += qv[j] * kvv[j]; sglob += qv[j] * gv[j]; }
  sself += __shfl_xor(sself, 1); sself += __shfl_xor(sself, 2);
  sglob += __shfl_xor(sglob, 1); sglob += __shfl_xor(sglob, 2);
  const float scale = 0.125f;
  sself *= scale; sglob *= scale;
  const float mm = fmaxf(sself, sglob);
  float p0 = __expf(sself - mm), p1 = __expf(sglob - mm);
  const float inv = 1.f / (p0 + p1);
  p0 *= inv; p1 *= inv;
  float* crow = ctx + rowoff + head * 64 + dp;
#pragma unroll
  for (int j4 = 0; j4 < 4; j4++) {
    float4 o;
    o.x = p0 * kvv[j4 * 4 + 0] + p1 * gv[j4 * 4 + 0];
    o.y = p0 * kvv[j4 * 4 + 1] + p1 * gv[j4 * 4 + 1];
    o.z = p0 * kvv[j4 * 4 + 2] + p1 * gv[j4 * 4 + 2];
    o.w = p0 * kvv[j4 * 4 + 3] + p1 * gv[j4 * 4 + 3];
    *(float4*)(crow + j4 * 4) = o;
  }
  if ((lane & 3) == 0) {
    const size_t li = ((size_t)(bb * NHEAD + head) * (NS - 1) + (s - 1)) * 2;
    lattn[li] = p0; lattn[li + 1] = p1;
  }
}

extern "C" void kernel_launch(void* const* d_in, const int* in_sizes, int n_in,
                              void* d_out, int out_size, void* d_ws, size_t ws_size,
                              hipStream_t stream) {
  const float* hs   = (const float*)d_in[0];
  const float* mask = (const float*)d_in[1];
  const float* Wq   = (const float*)d_in[2];
  const float* bq   = (const float*)d_in[3];
  const float* Wkv  = (const float*)d_in[4];
  const float* bkv  = (const float*)d_in[5];
  float* ctx   = (float*)d_out;
  float* lattn = ctx + (size_t)NB * NS * NHID;  // 33,554,432

  __bf16* hsb = (__bf16*)d_ws;                       // 33,554,432 elems
  __bf16* Wb  = hsb + (size_t)33554432;              //  2,097,152
  __bf16* Qb  = Wb  + (size_t)2097152;               // 33,554,432
  __bf16* KVb = Qb  + (size_t)33554432;              // 33,554,432
  float*  gvec = (float*)(KVb + (size_t)33554432);   //      8,192 f32

  cast_f32_to_bf16<<<4096, 256, 0, stream>>>(hs, hsb, 33554432);
  cast_f32_to_bf16<<<512, 256, 0, stream>>>(Wq, Wb, 1048576);
  cast_f32_to_bf16<<<512, 256, 0, stream>>>(Wkv, Wb + (size_t)1048576, 1048576);
  gemm_qkv<<<4096, 256, 0, stream>>>(hsb, Wb, bq, bkv, Qb, KVb);
  global_attn<<<NB * NHEAD, 256, 0, stream>>>(Qb, KVb, mask, gvec, ctx);
  local_attn<<<NB * (NS / 4), 256, 0, stream>>>(Qb, KVb, gvec, ctx, lattn);
}

// Round 2
// 531.725 us; speedup vs baseline: 1.5068x; 1.5068x over previous
//
#include <hip/hip_runtime.h>
#include <hip/hip_bf16.h>
#include <stdint.h>

#define NB 8
#define NS 4096
#define NHID 1024
#define NHEAD 16
#define ND 64
#define NCH 16      // S-chunks per (b,h) for global attention
#define CHUNK 256   // NS / NCH

typedef __attribute__((ext_vector_type(8))) __bf16 bf16x8;
typedef __attribute__((ext_vector_type(4))) __bf16 bf16x4;
typedef __attribute__((ext_vector_type(4))) float floatx4;

__device__ __forceinline__ void async_copy16(const __bf16* g, __bf16* l) {
  __builtin_amdgcn_global_load_lds(
      (const __attribute__((address_space(1))) void*)g,
      (__attribute__((address_space(3))) void*)l,
      16, 0, 0);
}

__global__ void cast_f32_to_bf16(const float* __restrict__ in,
                                 __bf16* __restrict__ out, int n) {
  int i = (blockIdx.x * blockDim.x + threadIdx.x) * 4;
  int stride = gridDim.x * blockDim.x * 4;
  for (; i < n; i += stride) {
    float4 v = *(const float4*)(in + i);
    bf16x4 o;
    o[0] = (__bf16)v.x; o[1] = (__bf16)v.y; o[2] = (__bf16)v.z; o[3] = (__bf16)v.w;
    *(bf16x4*)(out + i) = o;
  }
}

// C[row, col] = sum_k A[row,k] * W[col,k]  (+bias); col<1024 -> Q, else KV.
__global__ __launch_bounds__(256) void gemm_qkv(
    const __bf16* __restrict__ A,   // [32768][1024]
    const __bf16* __restrict__ W,   // [2048][1024] rows: 0..1023 Wq, 1024..2047 Wkv
    const float* __restrict__ bq, const float* __restrict__ bkv,
    __bf16* __restrict__ Q, __bf16* __restrict__ KV) {
  __shared__ __align__(16) __bf16 As[128 * 64];
  __shared__ __align__(16) __bf16 Bs[128 * 64];
  const int tid  = threadIdx.x;
  const int lane = tid & 63;
  const int wid  = tid >> 6;
  const int tn = blockIdx.x & 15;   // N fastest: 16 consecutive blocks share A panel
  const int tm = blockIdx.x >> 4;
  const int rowBase = tm * 128;
  const int colBase = tn * 128;
  const int wm = wid >> 1, wn = wid & 1;

  floatx4 acc[4][4];
#pragma unroll
  for (int m = 0; m < 4; m++)
#pragma unroll
    for (int n = 0; n < 4; n++)
#pragma unroll
      for (int j = 0; j < 4; j++) acc[m][n][j] = 0.f;

  const int lrow = lane >> 3;        // 0..7
  const int lk   = (lane & 7) * 8;   // 0..56

  for (int kt = 0; kt < 1024; kt += 64) {
#pragma unroll
    for (int i = 0; i < 4; ++i) {
      const int chunk = wid * 4 + i;        // 0..15
      const int r = chunk * 8 + lrow;       // 0..127
      async_copy16(A + (size_t)(rowBase + r) * 1024 + kt + lk, &As[chunk * 512]);
      async_copy16(W + (size_t)(colBase + r) * 1024 + kt + lk, &Bs[chunk * 512]);
    }
    __syncthreads();
#pragma unroll
    for (int ks = 0; ks < 64; ks += 32) {
      bf16x8 af[4], bfr[4];
#pragma unroll
      for (int m = 0; m < 4; m++)
        af[m] = *(const bf16x8*)&As[(wm * 64 + m * 16 + (lane & 15)) * 64 + ks + (lane >> 4) * 8];
#pragma unroll
      for (int n = 0; n < 4; n++)
        bfr[n] = *(const bf16x8*)&Bs[(wn * 64 + n * 16 + (lane & 15)) * 64 + ks + (lane >> 4) * 8];
#pragma unroll
      for (int m = 0; m < 4; m++)
#pragma unroll
        for (int n = 0; n < 4; n++)
          acc[m][n] = __builtin_amdgcn_mfma_f32_16x16x32_bf16(af[m], bfr[n], acc[m][n], 0, 0, 0);
    }
    __syncthreads();
  }
  // epilogue: C/D layout col=lane&15, row=(lane>>4)*4+j
  const int crow0 = (lane >> 4) * 4;
  const int ccol  = lane & 15;
#pragma unroll
  for (int m = 0; m < 4; m++) {
#pragma unroll
    for (int n = 0; n < 4; n++) {
      const int col = colBase + wn * 64 + n * 16 + ccol;
      const float bias = (col < 1024) ? bq[col] : bkv[col - 1024];
#pragma unroll
      for (int j = 0; j < 4; j++) {
        const int row = rowBase + wm * 64 + m * 16 + crow0 + j;
        const float v = acc[m][n][j] + bias;
        if (col < 1024) Q[(size_t)row * 1024 + col] = (__bf16)v;
        else            KV[(size_t)row * 1024 + (col - 1024)] = (__bf16)v;
      }
    }
  }
}

// Phase 1: one block per (b, h, chunk). Partial softmax + weighted vec over
// CHUNK rows of K. Writes {chunk max, chunk expsum, chunk weighted vec[64]}.
__global__ __launch_bounds__(256) void global_attn_p1(
    const __bf16* __restrict__ Q, const __bf16* __restrict__ KV,
    const float* __restrict__ mask,
    float* __restrict__ pm, float* __restrict__ ps, float* __restrict__ pv) {
  __shared__ float gq[64];
  __shared__ float sc[CHUNK];
  __shared__ float red[256];
  const int bid = blockIdx.x;          // ((b*16 + h)*NCH + c)
  const int c = bid & (NCH - 1);
  const int h = (bid >> 4) & 15;
  const int b = bid >> 8;
  const int tid = threadIdx.x;
  const float scale = 0.125f;

  if (tid < 64) gq[tid] = (float)Q[(size_t)(b * NS) * NHID + h * 64 + tid];
  __syncthreads();

  const int s = c * CHUNK + tid;       // one row per thread
  const __bf16* kr = KV + (size_t)(b * NS + s) * NHID + h * 64;
  float dot = 0.f;
#pragma unroll
  for (int d0 = 0; d0 < 64; d0 += 8) {
    bf16x8 kv8 = *(const bf16x8*)(kr + d0);
#pragma unroll
    for (int j = 0; j < 8; j++) dot += gq[d0 + j] * (float)kv8[j];
  }
  const float score = dot * scale + mask[b * NS + s];

  // block max
  red[tid] = score; __syncthreads();
#pragma unroll
  for (int off = 128; off > 0; off >>= 1) {
    if (tid < off) red[tid] = fmaxf(red[tid], red[tid + off]);
    __syncthreads();
  }
  const float mc = red[0]; __syncthreads();

  const float p = __expf(score - mc);
  sc[tid] = p;
  red[tid] = p; __syncthreads();
#pragma unroll
  for (int off = 128; off > 0; off >>= 1) {
    if (tid < off) red[tid] += red[tid + off];
    __syncthreads();
  }
  const float sumc = red[0]; __syncthreads();

  // weighted vec: lane d accumulates over 64 rows of its quarter (L2-hot re-read)
  const int d = tid & 63;
  const int g = tid >> 6;
  const __bf16* kcol = KV + (size_t)(b * NS + c * CHUNK + g * 64) * NHID + h * 64 + d;
  float acc = 0.f;
#pragma unroll 8
  for (int r = 0; r < 64; r++)
    acc += sc[g * 64 + r] * (float)kcol[(size_t)r * NHID];
  red[tid] = acc; __syncthreads();
  if (tid < 64) {
    pv[(size_t)bid * 64 + tid] = red[tid] + red[tid + 64] + red[tid + 128] + red[tid + 192];
    if (tid == 0) { pm[bid] = mc; ps[bid] = sumc; }
  }
}

// Phase 2: one 64-thread block per (b,h). Combine NCH chunk partials.
__global__ __launch_bounds__(64) void global_attn_p2(
    const float* __restrict__ pm, const float* __restrict__ ps,
    const float* __restrict__ pv,
    float* __restrict__ gvec, float* __restrict__ ctx) {
  const int bh = blockIdx.x;           // 0..127
  const int lane = threadIdx.x;        // 0..63
  const int base = bh * NCH;
  float M = -1e30f;
#pragma unroll
  for (int c = 0; c < NCH; c++) M = fmaxf(M, pm[base + c]);
  float tot = 0.f, vec = 0.f;
#pragma unroll
  for (int c = 0; c < NCH; c++) {
    const float w = __expf(pm[base + c] - M);
    tot += ps[base + c] * w;
    vec += pv[(size_t)(base + c) * 64 + lane] * w;
  }
  const float gout = vec / tot;
  const int b = bh >> 4, h = bh & 15;
  gvec[bh * 64 + lane] = gout;
  ctx[(size_t)(b * NS) * NHID + h * 64 + lane] = gout;  // ctx row s=0
}

// One wave per (b, s>=1); 4 lanes per head.
__global__ __launch_bounds__(256) void local_attn(
    const __bf16* __restrict__ Q, const __bf16* __restrict__ KV,
    const float* __restrict__ gvec, float* __restrict__ ctx,
    float* __restrict__ lattn) {
  __shared__ float gs[NHEAD * 64];
  const int bb = blockIdx.x >> 10;
  const int s0 = (blockIdx.x & 1023) * 4;
  const int tid = threadIdx.x;
  for (int i = tid; i < NHEAD * 64; i += 256) gs[i] = gvec[bb * NHEAD * 64 + i];
  __syncthreads();
  const int wid = tid >> 6, lane = tid & 63;
  const int s = s0 + wid;
  if (s == 0) return;  // row 0 written by global_attn_p2
  const int head = lane >> 2;
  const int dp = (lane & 3) * 16;
  const size_t rowoff = (size_t)(bb * NS + s) * NHID;
  const __bf16* qr = Q + rowoff + head * 64 + dp;
  const __bf16* kr = KV + rowoff + head * 64 + dp;
  float qv[16], kvv[16], gv[16];
  bf16x8 q0 = *(const bf16x8*)qr, q1 = *(const bf16x8*)(qr + 8);
  bf16x8 k0 = *(const bf16x8*)kr, k1 = *(const bf16x8*)(kr + 8);
#pragma unroll
  for (int j = 0; j < 8; j++) {
    qv[j] = (float)q0[j]; qv[j + 8] = (float)q1[j];
    kvv[j] = (float)k0[j]; kvv[j + 8] = (float)k1[j];
  }
#pragma unroll
  for (int j = 0; j < 16; j++) gv[j] = gs[head * 64 + dp + j];
  float sself = 0.f, sglob = 0.f;
#pragma unroll
  for (int j = 0; j < 16; j++) { sself += qv[j] * kvv[j]; sglob += qv[j] * gv[j]; }
  sself += __shfl_xor(sself, 1); sself += __shfl_xor(sself, 2);
  sglob += __shfl_xor(sglob, 1); sglob += __shfl_xor(sglob, 2);
  const float scale = 0.125f;
  sself *= scale; sglob *= scale;
  const float mm = fmaxf(sself, sglob);
  float p0 = __expf(sself - mm), p1 = __expf(sglob - mm);
  const float inv = 1.f / (p0 + p1);
  p0 *= inv; p1 *= inv;
  float* crow = ctx + rowoff + head * 64 + dp;
#pragma unroll
  for (int j4 = 0; j4 < 4; j4++) {
    float4 o;
    o.x = p0 * kvv[j4 * 4 + 0] + p1 * gv[j4 * 4 + 0];
    o.y = p0 * kvv[j4 * 4 + 1] + p1 * gv[j4 * 4 + 1];
    o.z = p0 * kvv[j4 * 4 + 2] + p1 * gv[j4 * 4 + 2];
    o.w = p0 * kvv[j4 * 4 + 3] + p1 * gv[j4 * 4 + 3];
    *(float4*)(crow + j4 * 4) = o;
  }
  if ((lane & 3) == 0) {
    const size_t li = ((size_t)(bb * NHEAD + head) * (NS - 1) + (s - 1)) * 2;
    lattn[li] = p0; lattn[li + 1] = p1;
  }
}

extern "C" void kernel_launch(void* const* d_in, const int* in_sizes, int n_in,
                              void* d_out, int out_size, void* d_ws, size_t ws_size,
                              hipStream_t stream) {
  const float* hs   = (const float*)d_in[0];
  const float* mask = (const float*)d_in[1];
  const float* Wq   = (const float*)d_in[2];
  const float* bq   = (const float*)d_in[3];
  const float* Wkv  = (const float*)d_in[4];
  const float* bkv  = (const float*)d_in[5];
  float* ctx   = (float*)d_out;
  float* lattn = ctx + (size_t)NB * NS * NHID;  // 33,554,432

  __bf16* hsb = (__bf16*)d_ws;                       // 33,554,432 elems
  __bf16* Wb  = hsb + (size_t)33554432;              //  2,097,152
  __bf16* Qb  = Wb  + (size_t)2097152;               // 33,554,432
  __bf16* KVb = Qb  + (size_t)33554432;              // 33,554,432
  float*  gvec = (float*)(KVb + (size_t)33554432);   //  8,192 f32
  float*  pm   = gvec + 8192;                        //  2,048 f32
  float*  ps   = pm + 2048;                          //  2,048 f32
  float*  pv   = ps + 2048;                          //  131,072 f32

  cast_f32_to_bf16<<<4096, 256, 0, stream>>>(hs, hsb, 33554432);
  cast_f32_to_bf16<<<512, 256, 0, stream>>>(Wq, Wb, 1048576);
  cast_f32_to_bf16<<<512, 256, 0, stream>>>(Wkv, Wb + (size_t)1048576, 1048576);
  gemm_qkv<<<4096, 256, 0, stream>>>(hsb, Wb, bq, bkv, Qb, KVb);
  global_attn_p1<<<NB * NHEAD * NCH, 256, 0, stream>>>(Qb, KVb, mask, pm, ps, pv);
  global_attn_p2<<<NB * NHEAD, 64, 0, stream>>>(pm, ps, pv, gvec, ctx);
  local_attn<<<NB * (NS / 4), 256, 0, stream>>>(Qb, KVb, gvec, ctx, lattn);
}

// Round 3
// 461.395 us; speedup vs baseline: 1.7365x; 1.1524x over previous
//
#include <hip/hip_runtime.h>
#include <hip/hip_bf16.h>
#include <stdint.h>

#define NB 8
#define NS 4096
#define NHID 1024
#define NHEAD 16
#define ND 64
#define NCH 16      // S-chunks per (b,h) for global attention
#define CHUNK 256   // NS / NCH
#define NT 16       // K-tiles in GEMM (K=1024, BK=64)

typedef __attribute__((ext_vector_type(8))) __bf16 bf16x8;
typedef __attribute__((ext_vector_type(4))) __bf16 bf16x4;
typedef __attribute__((ext_vector_type(4))) float floatx4;

__device__ __forceinline__ void async_copy16(const __bf16* g, __bf16* l) {
  __builtin_amdgcn_global_load_lds(
      (const __attribute__((address_space(1))) void*)g,
      (__attribute__((address_space(3))) void*)l,
      16, 0, 0);
}

__global__ void cast_f32_to_bf16(const float* __restrict__ in,
                                 __bf16* __restrict__ out, int n) {
  int i = (blockIdx.x * blockDim.x + threadIdx.x) * 4;
  int stride = gridDim.x * blockDim.x * 4;
  for (; i < n; i += stride) {
    float4 v = *(const float4*)(in + i);
    bf16x4 o;
    o[0] = (__bf16)v.x; o[1] = (__bf16)v.y; o[2] = (__bf16)v.z; o[3] = (__bf16)v.w;
    *(bf16x4*)(out + i) = o;
  }
}

// ---------------- 256x256 8-phase GEMM (T2+T3+T4+T5) ----------------
// C[row,col] = sum_k A[row,k]*W[col,k] + bias. cols<1024 -> Q, else KV.
// LDS layout per matrix slot: [kh(2)][row(256)][k(32)] bf16, 64B rows,
// XOR-swizzled: phys = logical ^ (((logical>>7)&3)<<4) (16B-chunk XOR).
// A slots at 0 / 32768; B slots at 65536 / 98304. Total 128 KiB.

__device__ __forceinline__ void stage_half(const __bf16* __restrict__ G, int rb,
                                           int T, int kh, int matB,
                                           char* smem, int tid, int wid) {
  const uint32_t regionOff = (matB ? 65536u : 0u) + (uint32_t)(T & 1) * 32768u
                           + (uint32_t)kh * 16384u;
#pragma unroll
  for (int j = 0; j < 2; ++j) {
    uint32_t P = (uint32_t)(j * 512 + tid) * 16u;        // phys LDS byte in region
    uint32_t L = P ^ (((P >> 7) & 3u) << 4);             // logical byte (involution)
    uint32_t r = L >> 6;                                 // row 0..255
    uint32_t c = (L >> 4) & 3u;                          // 16B chunk in row
    const __bf16* src = G + (size_t)(rb + (int)r) * 1024 + T * 64 + kh * 32 + (int)c * 8;
    async_copy16(src, (__bf16*)(smem + regionOff + (uint32_t)j * 8192u
                                + (uint32_t)wid * 1024u));
  }
}

__device__ __forceinline__ bf16x8 lds_frag(const char* smem, uint32_t base,
                                           int kk, int row, int hi4) {
  uint32_t Lrel = (uint32_t)kk * 16384u + (uint32_t)row * 64u + (uint32_t)hi4 * 16u;
  uint32_t phys = Lrel ^ (((Lrel >> 7) & 3u) << 4);
  return *(const bf16x8*)(smem + base + phys);
}

#define BARRIER asm volatile("s_barrier" ::: "memory")
#define WAIT_LGKM0 asm volatile("s_waitcnt lgkmcnt(0)" ::: "memory")
#define VM8 asm volatile("s_waitcnt vmcnt(8)" ::: "memory")
#define VM4 asm volatile("s_waitcnt vmcnt(4)" ::: "memory")
#define VM0 asm volatile("s_waitcnt vmcnt(0)" ::: "memory")

// One phase: ds-read fragments, issue one half-tile prefetch, barrier,
// lgkmcnt(0), prio-boosted 16 MFMA, optional counted vmcnt, barrier.
#define PHASE(KK, FMB, READB, STAGE_STMT, DRAIN_STMT)                          \
  do {                                                                         \
    if (READB) {                                                               \
      _Pragma("unroll")                                                        \
      for (int fn = 0; fn < 4; ++fn)                                           \
        bfrag[fn] = lds_frag(smem, 65536u + sl, KK, wn * 64 + fn * 16 + l15, hi4); \
    }                                                                          \
    _Pragma("unroll")                                                          \
    for (int fi = 0; fi < 4; ++fi)                                             \
      afrag[fi] = lds_frag(smem, sl, KK, wm * 128 + (FMB + fi) * 16 + l15, hi4); \
    STAGE_STMT;                                                                \
    BARRIER;                                                                   \
    WAIT_LGKM0;                                                                \
    __builtin_amdgcn_s_setprio(1);                                             \
    _Pragma("unroll")                                                          \
    for (int fi = 0; fi < 4; ++fi) {                                           \
      _Pragma("unroll")                                                        \
      for (int fn = 0; fn < 4; ++fn)                                           \
        acc[FMB + fi][fn] = __builtin_amdgcn_mfma_f32_16x16x32_bf16(           \
            afrag[fi], bfrag[fn], acc[FMB + fi][fn], 0, 0, 0);                 \
    }                                                                          \
    __builtin_amdgcn_s_setprio(0);                                             \
    DRAIN_STMT;                                                                \
    BARRIER;                                                                   \
  } while (0)

__global__ __launch_bounds__(512, 2) void gemm_qkv(
    const __bf16* __restrict__ A,   // [32768][1024]
    const __bf16* __restrict__ W,   // [2048][1024]
    const float* __restrict__ bq, const float* __restrict__ bkv,
    __bf16* __restrict__ Q, __bf16* __restrict__ KV) {
  __shared__ __align__(1024) char smem[131072];
  const int tid = threadIdx.x;
  const int lane = tid & 63;
  const int wid = tid >> 6;     // 0..7
  const int wm = wid >> 2;      // 0..1
  const int wn = wid & 3;       // 0..3
  const int l15 = lane & 15;
  const int hi4 = lane >> 4;

  // bijective XCD swizzle: nwg=1024, 1024%8==0
  const int bid = blockIdx.x;
  const int swz = ((bid & 7) << 7) | (bid >> 3);
  const int tn = swz & 7;       // N fastest within an XCD chunk (A-panel L2 reuse)
  const int tm = swz >> 3;
  const int rowBase = tm * 256;
  const int colBase = tn * 256;

  floatx4 acc[8][4];
#pragma unroll
  for (int m = 0; m < 8; m++)
#pragma unroll
    for (int n = 0; n < 4; n++)
#pragma unroll
      for (int j = 0; j < 4; j++) acc[m][n][j] = 0.f;

  // Prologue: tile0 (4 halves) + tile1 kh0 (A,B). Drain tile0, keep 4 in flight.
  stage_half(A, rowBase, 0, 0, 0, smem, tid, wid);
  stage_half(W, colBase, 0, 0, 1, smem, tid, wid);
  stage_half(A, rowBase, 0, 1, 0, smem, tid, wid);
  stage_half(W, colBase, 0, 1, 1, smem, tid, wid);
  stage_half(A, rowBase, 1, 0, 0, smem, tid, wid);
  stage_half(W, colBase, 1, 0, 1, smem, tid, wid);
  VM4;
  BARRIER;

  bf16x8 afrag[4], bfrag[4];
#pragma unroll 1
  for (int t = 0; t < NT; ++t) {
    const uint32_t sl = (uint32_t)(t & 1) * 32768u;
    // ph1: kk0, rows 0-63; stage (t+1).A kh1
    PHASE(0, 0, 1,
          { if (t + 1 < NT) stage_half(A, rowBase, t + 1, 1, 0, smem, tid, wid); },
          ;);
    // ph2: kk0, rows 64-127 (reuse B); stage (t+1).B kh1; drain for next kk1 reads
    PHASE(0, 4, 0,
          { if (t + 1 < NT) stage_half(W, colBase, t + 1, 1, 1, smem, tid, wid); },
          { if (t < NT - 1) { VM8; } else { VM0; } });
    // ph3: kk1, rows 0-63; stage (t+2).A kh0
    PHASE(1, 0, 1,
          { if (t + 2 < NT) stage_half(A, rowBase, t + 2, 0, 0, smem, tid, wid); },
          ;);
    // ph4: kk1, rows 64-127; stage (t+2).B kh0; drain for next tile's kk0 reads
    PHASE(1, 4, 0,
          { if (t + 2 < NT) stage_half(W, colBase, t + 2, 0, 1, smem, tid, wid); },
          { if (t < NT - 2) { VM8; } else if (t == NT - 2) { VM4; } });
  }

  // Epilogue: C/D layout col=lane&15, row=(lane>>4)*4+j. Q/KV + bias uniform per block.
  const bool isQ = (colBase < 1024);
  __bf16* __restrict__ dst = isQ ? Q : KV;
  const float* __restrict__ bias = isQ ? bq : bkv;
  const int colOff = isQ ? colBase : (colBase - 1024);
#pragma unroll
  for (int fm = 0; fm < 8; fm++) {
#pragma unroll
    for (int fn = 0; fn < 4; fn++) {
      const int col = colOff + wn * 64 + fn * 16 + l15;
      const float bv = bias[col];
#pragma unroll
      for (int j = 0; j < 4; j++) {
        const int row = rowBase + wm * 128 + fm * 16 + hi4 * 4 + j;
        dst[(size_t)row * 1024 + col] = (__bf16)(acc[fm][fn][j] + bv);
      }
    }
  }
}

// Phase 1: one block per (b, h, chunk). Partial softmax + weighted vec over
// CHUNK rows of K. Writes {chunk max, chunk expsum, chunk weighted vec[64]}.
__global__ __launch_bounds__(256) void global_attn_p1(
    const __bf16* __restrict__ Q, const __bf16* __restrict__ KV,
    const float* __restrict__ mask,
    float* __restrict__ pm, float* __restrict__ ps, float* __restrict__ pv) {
  __shared__ float gq[64];
  __shared__ float sc[CHUNK];
  __shared__ float red[256];
  const int bid = blockIdx.x;          // ((b*16 + h)*NCH + c)
  const int c = bid & (NCH - 1);
  const int h = (bid >> 4) & 15;
  const int b = bid >> 8;
  const int tid = threadIdx.x;
  const float scale = 0.125f;

  if (tid < 64) gq[tid] = (float)Q[(size_t)(b * NS) * NHID + h * 64 + tid];
  __syncthreads();

  const int s = c * CHUNK + tid;       // one row per thread
  const __bf16* kr = KV + (size_t)(b * NS + s) * NHID + h * 64;
  float dot = 0.f;
#pragma unroll
  for (int d0 = 0; d0 < 64; d0 += 8) {
    bf16x8 kv8 = *(const bf16x8*)(kr + d0);
#pragma unroll
    for (int j = 0; j < 8; j++) dot += gq[d0 + j] * (float)kv8[j];
  }
  const float score = dot * scale + mask[b * NS + s];

  red[tid] = score; __syncthreads();
#pragma unroll
  for (int off = 128; off > 0; off >>= 1) {
    if (tid < off) red[tid] = fmaxf(red[tid], red[tid + off]);
    __syncthreads();
  }
  const float mc = red[0]; __syncthreads();

  const float p = __expf(score - mc);
  sc[tid] = p;
  red[tid] = p; __syncthreads();
#pragma unroll
  for (int off = 128; off > 0; off >>= 1) {
    if (tid < off) red[tid] += red[tid + off];
    __syncthreads();
  }
  const float sumc = red[0]; __syncthreads();

  const int d = tid & 63;
  const int g = tid >> 6;
  const __bf16* kcol = KV + (size_t)(b * NS + c * CHUNK + g * 64) * NHID + h * 64 + d;
  float acc = 0.f;
#pragma unroll 8
  for (int r = 0; r < 64; r++)
    acc += sc[g * 64 + r] * (float)kcol[(size_t)r * NHID];
  red[tid] = acc; __syncthreads();
  if (tid < 64) {
    pv[(size_t)bid * 64 + tid] = red[tid] + red[tid + 64] + red[tid + 128] + red[tid + 192];
    if (tid == 0) { pm[bid] = mc; ps[bid] = sumc; }
  }
}

// Phase 2: one 64-thread block per (b,h). Combine NCH chunk partials.
__global__ __launch_bounds__(64) void global_attn_p2(
    const float* __restrict__ pm, const float* __restrict__ ps,
    const float* __restrict__ pv,
    float* __restrict__ gvec, float* __restrict__ ctx) {
  const int bh = blockIdx.x;           // 0..127
  const int lane = threadIdx.x;        // 0..63
  const int base = bh * NCH;
  float M = -1e30f;
#pragma unroll
  for (int c = 0; c < NCH; c++) M = fmaxf(M, pm[base + c]);
  float tot = 0.f, vec = 0.f;
#pragma unroll
  for (int c = 0; c < NCH; c++) {
    const float w = __expf(pm[base + c] - M);
    tot += ps[base + c] * w;
    vec += pv[(size_t)(base + c) * 64 + lane] * w;
  }
  const float gout = vec / tot;
  const int b = bh >> 4, h = bh & 15;
  gvec[bh * 64 + lane] = gout;
  ctx[(size_t)(b * NS) * NHID + h * 64 + lane] = gout;  // ctx row s=0
}

// One wave per (b, s>=1); 4 lanes per head.
__global__ __launch_bounds__(256) void local_attn(
    const __bf16* __restrict__ Q, const __bf16* __restrict__ KV,
    const float* __restrict__ gvec, float* __restrict__ ctx,
    float* __restrict__ lattn) {
  __shared__ float gs[NHEAD * 64];
  const int bb = blockIdx.x >> 10;
  const int s0 = (blockIdx.x & 1023) * 4;
  const int tid = threadIdx.x;
  for (int i = tid; i < NHEAD * 64; i += 256) gs[i] = gvec[bb * NHEAD * 64 + i];
  __syncthreads();
  const int wid = tid >> 6, lane = tid & 63;
  const int s = s0 + wid;
  if (s == 0) return;  // row 0 written by global_attn_p2
  const int head = lane >> 2;
  const int dp = (lane & 3) * 16;
  const size_t rowoff = (size_t)(bb * NS + s) * NHID;
  const __bf16* qr = Q + rowoff + head * 64 + dp;
  const __bf16* kr = KV + rowoff + head * 64 + dp;
  float qv[16], kvv[16], gv[16];
  bf16x8 q0 = *(const bf16x8*)qr, q1 = *(const bf16x8*)(qr + 8);
  bf16x8 k0 = *(const bf16x8*)kr, k1 = *(const bf16x8*)(kr + 8);
#pragma unroll
  for (int j = 0; j < 8; j++) {
    qv[j] = (float)q0[j]; qv[j + 8] = (float)q1[j];
    kvv[j] = (float)k0[j]; kvv[j + 8] = (float)k1[j];
  }
#pragma unroll
  for (int j = 0; j < 16; j++) gv[j] = gs[head * 64 + dp + j];
  float sself = 0.f, sglob = 0.f;
#pragma unroll
  for (int j = 0; j < 16; j++) { sself += qv[j] * kvv[j]; sglob += qv[j] * gv[j]; }
  sself += __shfl_xor(sself, 1); sself += __shfl_xor(sself, 2);
  sglob += __shfl_xor(sglob, 1); sglob += __shfl_xor(sglob, 2);
  const float scale = 0.125f;
  sself *= scale; sglob *= scale;
  const float mm = fmaxf(sself, sglob);
  float p0 = __expf(sself - mm), p1 = __expf(sglob - mm);
  const float inv = 1.f / (p0 + p1);
  p0 *= inv; p1 *= inv;
  float* crow = ctx + rowoff + head * 64 + dp;
#pragma unroll
  for (int j4 = 0; j4 < 4; j4++) {
    float4 o;
    o.x = p0 * kvv[j4 * 4 + 0] + p1 * gv[j4 * 4 + 0];
    o.y = p0 * kvv[j4 * 4 + 1] + p1 * gv[j4 * 4 + 1];
    o.z = p0 * kvv[j4 * 4 + 2] + p1 * gv[j4 * 4 + 2];
    o.w = p0 * kvv[j4 * 4 + 3] + p1 * gv[j4 * 4 + 3];
    *(float4*)(crow + j4 * 4) = o;
  }
  if ((lane & 3) == 0) {
    const size_t li = ((size_t)(bb * NHEAD + head) * (NS - 1) + (s - 1)) * 2;
    lattn[li] = p0; lattn[li + 1] = p1;
  }
}

extern "C" void kernel_launch(void* const* d_in, const int* in_sizes, int n_in,
                              void* d_out, int out_size, void* d_ws, size_t ws_size,
                              hipStream_t stream) {
  const float* hs   = (const float*)d_in[0];
  const float* mask = (const float*)d_in[1];
  const float* Wq   = (const float*)d_in[2];
  const float* bq   = (const float*)d_in[3];
  const float* Wkv  = (const float*)d_in[4];
  const float* bkv  = (const float*)d_in[5];
  float* ctx   = (float*)d_out;
  float* lattn = ctx + (size_t)NB * NS * NHID;  // 33,554,432

  __bf16* hsb = (__bf16*)d_ws;                       // 33,554,432 elems
  __bf16* Wb  = hsb + (size_t)33554432;              //  2,097,152
  __bf16* Qb  = Wb  + (size_t)2097152;               // 33,554,432
  __bf16* KVb = Qb  + (size_t)33554432;              // 33,554,432
  float*  gvec = (float*)(KVb + (size_t)33554432);   //  8,192 f32
  float*  pm   = gvec + 8192;                        //  2,048 f32
  float*  ps   = pm + 2048;                          //  2,048 f32
  float*  pv   = ps + 2048;                          //  131,072 f32

  cast_f32_to_bf16<<<4096, 256, 0, stream>>>(hs, hsb, 33554432);
  cast_f32_to_bf16<<<512, 256, 0, stream>>>(Wq, Wb, 1048576);
  cast_f32_to_bf16<<<512, 256, 0, stream>>>(Wkv, Wb + (size_t)1048576, 1048576);
  gemm_qkv<<<1024, 512, 0, stream>>>(hsb, Wb, bq, bkv, Qb, KVb);
  global_attn_p1<<<NB * NHEAD * NCH, 256, 0, stream>>>(Qb, KVb, mask, pm, ps, pv);
  global_attn_p2<<<NB * NHEAD, 64, 0, stream>>>(pm, ps, pv, gvec, ctx);
  local_attn<<<NB * (NS / 4), 256, 0, stream>>>(Qb, KVb, gvec, ctx, lattn);
}